// Round 1
// baseline (1315.504 us; speedup 1.0000x reference)
//
#include <hip/hip_runtime.h>
#include <hip/hip_bf16.h>

// ---------------------------------------------------------------------------
// QuadrupletInteraction (GemNet-style), MI355X / gfx950.
// Pipeline: k1 (m@W_db fused rbf, bf16 MFMA) -> k2 (down-proj) -> k3 (cbf mul
// + edge->trip gather) -> k4 (ragged bilinear, per-edge MFMA vs W_bil) ->
// k5 (up-projections + swap + combine).
// Intermediates in d_ws (185.6 MB): x1 bf16 | x2 bf16 | t bf16 | x f32.
// Error budget: bf16-rounded GEMM inputs, f32 accumulation everywhere;
// threshold is 2% of max|ref| (bf16 mode), we target ~0.5% worst-path.
// ---------------------------------------------------------------------------

constexpr int NE   = 100000;   // edges
constexpr int ED   = 512;      // E
constexpr int NT   = 1000000;  // triplets
constexpr int NQ   = 2000000;  // quadruplets
constexpr int QI   = 32;       // QIN
constexpr int QO   = 32;       // QOUT
constexpr int RBF_ = 16;
constexpr int CBF_ = 16;
constexpr int SBF_ = 32;
constexpr int NSPH_= 7;
constexpr int KAVG_= 20;

typedef float f32x4 __attribute__((ext_vector_type(4)));
typedef __bf16 bf16x8 __attribute__((ext_vector_type(8)));

__device__ __forceinline__ float silu_f(float v) {
    return __fdividef(v, 1.0f + __expf(-v));
}

// MFMA 16x16x32 bf16 layouts (m89-verified):
//   A frag: lane holds A[m = lane&15][k = (lane>>4)*8 + j], j=0..7 (contiguous k)
//   B frag: lane holds B[k = (lane>>4)*8 + j][n = lane&15]
//   C/D   : col = lane&15, row = (lane>>4)*4 + reg
// LDS tiles stored row-major with rows padded to 40 bf16 (80 B = 5*16B: b128-
// aligned, 20-dword stride spreads banks 2-way = free).

// ---------------- k1: x1 = bf16( silu(m@W_db) * (rad@W_rbf) * s_rbf ) -------
__global__ __launch_bounds__(256) void k1(const float* __restrict__ mM,
                                          const float* __restrict__ rad,
                                          const float* __restrict__ Wdb,
                                          const float* __restrict__ Wrbf,
                                          const float* __restrict__ s_rbf,
                                          __bf16* __restrict__ x1)
{
    constexpr int BM = 128, BN = 128, BK = 32, LP = 40;
    __shared__ __bf16 As[BM * LP];
    __shared__ __bf16 Bs[BN * LP];

    const int tid  = threadIdx.x;
    const int lane = tid & 63, wv = tid >> 6;
    const int ml = lane & 15, qd = lane >> 4;
    const int row0 = blockIdx.x * BM, col0 = blockIdx.y * BN;
    const int wm = (wv >> 1) * 64, wn = (wv & 1) * 64;

    f32x4 acc[4][4], accR[4][4];
    const f32x4 vz = {0.f, 0.f, 0.f, 0.f};
#pragma unroll
    for (int i = 0; i < 4; i++)
#pragma unroll
        for (int j = 0; j < 4; j++) { acc[i][j] = vz; accR[i][j] = vz; }

    for (int k0 = 0; k0 < ED; k0 += BK) {
        __syncthreads();
        // stage A: 128x32 f32 -> bf16 (1024 float4 loads)
#pragma unroll
        for (int f = tid; f < BM * 8; f += 256) {
            int r = f >> 3, c4 = (f & 7) * 4;
            float4 v = make_float4(0.f, 0.f, 0.f, 0.f);
            if (row0 + r < NE) v = *(const float4*)(mM + (size_t)(row0 + r) * ED + k0 + c4);
            __bf16* d = &As[r * LP + c4];
            d[0] = (__bf16)v.x; d[1] = (__bf16)v.y; d[2] = (__bf16)v.z; d[3] = (__bf16)v.w;
        }
        // stage B transposed: Bs[n][k] so B-frag reads are contiguous
#pragma unroll
        for (int f = tid; f < 1024; f += 256) {
            int kr = f >> 5, c4 = (f & 31) * 4;
            float4 v = *(const float4*)(Wdb + (size_t)(k0 + kr) * ED + col0 + c4);
            Bs[(c4 + 0) * LP + kr] = (__bf16)v.x;
            Bs[(c4 + 1) * LP + kr] = (__bf16)v.y;
            Bs[(c4 + 2) * LP + kr] = (__bf16)v.z;
            Bs[(c4 + 3) * LP + kr] = (__bf16)v.w;
        }
        __syncthreads();
        bf16x8 af[4], bfr[4];
#pragma unroll
        for (int i = 0; i < 4; i++) {
            af[i]  = *(const bf16x8*)&As[(wm + i * 16 + ml) * LP + qd * 8];
            bfr[i] = *(const bf16x8*)&Bs[(wn + i * 16 + ml) * LP + qd * 8];
        }
#pragma unroll
        for (int mt = 0; mt < 4; mt++)
#pragma unroll
            for (int nt = 0; nt < 4; nt++)
                acc[mt][nt] = __builtin_amdgcn_mfma_f32_16x16x32_bf16(af[mt], bfr[nt], acc[mt][nt], 0, 0, 0);
    }

    // rbf pass: accR = rad(128x16, zero-padded K=32) @ Wrbf(16x128)
    __syncthreads();
#pragma unroll
    for (int f = tid; f < BM * 8; f += 256) {
        int r = f >> 3, c4 = (f & 7) * 4;
        float4 v = make_float4(0.f, 0.f, 0.f, 0.f);
        if (c4 < RBF_ && row0 + r < NE) v = *(const float4*)(rad + (size_t)(row0 + r) * RBF_ + c4);
        __bf16* d = &As[r * LP + c4];
        d[0] = (__bf16)v.x; d[1] = (__bf16)v.y; d[2] = (__bf16)v.z; d[3] = (__bf16)v.w;
    }
#pragma unroll
    for (int f = tid; f < 1024; f += 256) {
        int kr = f >> 5, c4 = (f & 31) * 4;
        float4 v = make_float4(0.f, 0.f, 0.f, 0.f);
        if (kr < RBF_) v = *(const float4*)(Wrbf + (size_t)kr * ED + col0 + c4);
        Bs[(c4 + 0) * LP + kr] = (__bf16)v.x;
        Bs[(c4 + 1) * LP + kr] = (__bf16)v.y;
        Bs[(c4 + 2) * LP + kr] = (__bf16)v.z;
        Bs[(c4 + 3) * LP + kr] = (__bf16)v.w;
    }
    __syncthreads();
    {
        bf16x8 af[4], bfr[4];
#pragma unroll
        for (int i = 0; i < 4; i++) {
            af[i]  = *(const bf16x8*)&As[(wm + i * 16 + ml) * LP + qd * 8];
            bfr[i] = *(const bf16x8*)&Bs[(wn + i * 16 + ml) * LP + qd * 8];
        }
#pragma unroll
        for (int mt = 0; mt < 4; mt++)
#pragma unroll
            for (int nt = 0; nt < 4; nt++)
                accR[mt][nt] = __builtin_amdgcn_mfma_f32_16x16x32_bf16(af[mt], bfr[nt], accR[mt][nt], 0, 0, 0);
    }

    const float srbf = s_rbf[0];
#pragma unroll
    for (int mt = 0; mt < 4; mt++)
#pragma unroll
        for (int r = 0; r < 4; r++) {
            int rr = wm + mt * 16 + qd * 4 + r;
            int grow = row0 + rr;
            if (grow < NE) {
#pragma unroll
                for (int nt = 0; nt < 4; nt++) {
                    int cc = wn + nt * 16 + ml;
                    float v = silu_f(acc[mt][nt][r]) * accR[mt][nt][r] * srbf;
                    x1[(size_t)grow * ED + col0 + cc] = (__bf16)v;
                }
            }
        }
}

// ---------------- k2: x2 = bf16( silu(x1 @ W_down) ) ------------------------
__global__ __launch_bounds__(256) void k2(const __bf16* __restrict__ x1,
                                          const float* __restrict__ Wdown,
                                          __bf16* __restrict__ x2)
{
    constexpr int BM = 128, BK = 64, LPA = 72, LPB = 72;  // 72 bf16 = 144 B rows
    __shared__ __bf16 As[BM * LPA];
    __shared__ __bf16 Bs[QI * LPB];

    const int tid = threadIdx.x;
    const int lane = tid & 63, wv = tid >> 6;
    const int ml = lane & 15, qd = lane >> 4;
    const int row0 = blockIdx.x * BM;
    const int wm = wv * 32;

    f32x4 acc[2][2];
    const f32x4 vz = {0.f, 0.f, 0.f, 0.f};
#pragma unroll
    for (int i = 0; i < 2; i++) { acc[i][0] = vz; acc[i][1] = vz; }

    for (int k0 = 0; k0 < ED; k0 += BK) {
        __syncthreads();
        // A: 128x64 bf16, already bf16 -> uint4 copies
#pragma unroll
        for (int f = tid; f < 1024; f += 256) {
            int r = f >> 3, c8 = (f & 7) * 8;
            uint4 v = make_uint4(0u, 0u, 0u, 0u);
            if (row0 + r < NE) v = *(const uint4*)(x1 + (size_t)(row0 + r) * ED + k0 + c8);
            *(uint4*)&As[r * LPA + c8] = v;
        }
        // B: Wdown[k0+kr][c] -> Bs[c][kr]
#pragma unroll
        for (int f = tid; f < BK * QI; f += 256) {
            int kr = f >> 5, c = f & 31;
            Bs[c * LPB + kr] = (__bf16)Wdown[(size_t)(k0 + kr) * QI + c];
        }
        __syncthreads();
#pragma unroll
        for (int kk = 0; kk < 2; kk++) {
            bf16x8 b0 = *(const bf16x8*)&Bs[(0  + ml) * LPB + kk * 32 + qd * 8];
            bf16x8 b1 = *(const bf16x8*)&Bs[(16 + ml) * LPB + kk * 32 + qd * 8];
#pragma unroll
            for (int mt = 0; mt < 2; mt++) {
                bf16x8 a = *(const bf16x8*)&As[(wm + mt * 16 + ml) * LPA + kk * 32 + qd * 8];
                acc[mt][0] = __builtin_amdgcn_mfma_f32_16x16x32_bf16(a, b0, acc[mt][0], 0, 0, 0);
                acc[mt][1] = __builtin_amdgcn_mfma_f32_16x16x32_bf16(a, b1, acc[mt][1], 0, 0, 0);
            }
        }
    }
#pragma unroll
    for (int mt = 0; mt < 2; mt++)
#pragma unroll
        for (int nt = 0; nt < 2; nt++)
#pragma unroll
            for (int r = 0; r < 4; r++) {
                int grow = row0 + wm + mt * 16 + qd * 4 + r;
                int cc = nt * 16 + ml;
                if (grow < NE) x2[(size_t)grow * QI + cc] = (__bf16)silu_f(acc[mt][nt][r]);
            }
}

// ---------------- k3: t[q] = x2[idx_trip_in[q]] * (cir@W_cbf)[q] * s_cbf ----
__global__ __launch_bounds__(256) void k3(const float* __restrict__ cir,
                                          const float* __restrict__ Wcbf,
                                          const float* __restrict__ s_cbf,
                                          const int* __restrict__ trip_in,
                                          const __bf16* __restrict__ x2,
                                          __bf16* __restrict__ t)
{
    constexpr int TPB = 64;
    __shared__ float cirs[TPB * CBF_];
    __shared__ float wc[CBF_ * QI];
    __shared__ int eix[TPB];

    const int tid = threadIdx.x;
    const int t0 = blockIdx.x * TPB;
#pragma unroll
    for (int i = tid; i < TPB * CBF_; i += 256) {
        int r = i >> 4, c = i & 15;
        cirs[i] = cir[(size_t)(t0 + r) * CBF_ + c];
    }
#pragma unroll
    for (int i = tid; i < CBF_ * QI; i += 256) wc[i] = Wcbf[i];
    if (tid < TPB) eix[tid] = trip_in[t0 + tid];
    __syncthreads();

    const float sc = s_cbf[0];
    const int d = tid & 31, ts0 = tid >> 5;
#pragma unroll
    for (int p = 0; p < TPB / 8; p++) {
        int ts = ts0 + p * 8;
        float a = 0.f;
#pragma unroll
        for (int c = 0; c < CBF_; c++) a += cirs[ts * CBF_ + c] * wc[c * QI + d];
        float xv = (float)x2[(size_t)eix[ts] * QI + d];
        t[(size_t)(t0 + ts) * QI + d] = (__bf16)(xv * a * sc);
    }
}

// ---------------- k4: per-edge bilinear (sum_k -> rW -> @W_bil) -> x --------
// Exploits idx_out=q/20, idx_out_agg=q%20: edge e owns quads e*20..e*20+19;
// m_pad slots k>=20 are zero and are skipped.
__global__ __launch_bounds__(256) void k4(const __bf16* __restrict__ t,
                                          const float* __restrict__ sph,
                                          const float* __restrict__ sphW1,
                                          const float* __restrict__ Wbil,
                                          const float* __restrict__ s_sbf,
                                          const int* __restrict__ t2q,
                                          float* __restrict__ x)
{
    constexpr int BE = 32;
    __shared__ float sumk[BE * NSPH_ * 32];      // 28672 B, f32 for accuracy
    __shared__ float sphs[BE * KAVG_ * NSPH_];   // 17920 B
    __shared__ int   qidx[BE * KAVG_];           //  2560 B
    __shared__ __bf16 rws[32 * 72];              //  4608 B (A chunk, M=32,K=64)
    __shared__ __bf16 wbs[32 * 72];              //  4608 B (B chunk transposed)

    const int tid = threadIdx.x;
    const int e0 = blockIdx.x * BE;
    const int d = tid & 31, eg = tid >> 5;
    const int lane = tid & 63, wv = tid >> 6;
    const int ml = lane & 15, qd = lane >> 4;
    const int mt = wv & 1, nt = wv >> 1;

    for (int i = tid; i < BE * KAVG_ * NSPH_; i += 256) {
        int e = i / (KAVG_ * NSPH_), rem = i % (KAVG_ * NSPH_);
        sphs[i] = sph[((size_t)(e0 + e) * 32) * NSPH_ + rem];  // rem = k*7+s, k<20
    }
    for (int i = tid; i < BE * KAVG_; i += 256) qidx[i] = t2q[(size_t)e0 * KAVG_ + i];
    __syncthreads();

    // phase 1: sum_k[e][s][d] = sum_k sph[e,k,s] * t[trip(e,k)][d]
    for (int e = eg; e < BE; e += 8) {
        float a[NSPH_] = {0.f, 0.f, 0.f, 0.f, 0.f, 0.f, 0.f};
        for (int k = 0; k < KAVG_; k++) {
            int q = qidx[e * KAVG_ + k];
            float tv = (float)t[(size_t)q * QI + d];
            const float* s7 = &sphs[(e * KAVG_ + k) * NSPH_];
#pragma unroll
            for (int s = 0; s < NSPH_; s++) a[s] += s7[s] * tv;
        }
#pragma unroll
        for (int s = 0; s < NSPH_; s++) sumk[(e * NSPH_ + s) * 32 + d] = a[s];
    }
    __syncthreads();

    // phase 2: K-chunked GEMM  x = (rW flat) @ W_bil, K=1024 in 16 chunks of 64
    f32x4 acc = {0.f, 0.f, 0.f, 0.f};
    for (int kc = 0; kc < 16; kc++) {
        __syncthreads();
#pragma unroll
        for (int j = 0; j < 4; j++) {
            int e = eg + 8 * j;
#pragma unroll
            for (int is = 0; is < 2; is++) {
                int i = kc * 2 + is;
                const float* w1 = &sphW1[((size_t)(e0 + e) * SBF_ + i) * NSPH_];
                float v = 0.f;
#pragma unroll
                for (int s = 0; s < NSPH_; s++) v += w1[s] * sumk[(e * NSPH_ + s) * 32 + d];
                rws[e * 72 + is * 32 + d] = (__bf16)v;
            }
        }
#pragma unroll
        for (int f = tid; f < 2048; f += 256) {
            int kr = f >> 5, o = f & 31;
            wbs[o * 72 + kr] = (__bf16)Wbil[(size_t)(kc * 64 + kr) * QO + o];
        }
        __syncthreads();
#pragma unroll
        for (int kk = 0; kk < 2; kk++) {
            bf16x8 a = *(const bf16x8*)&rws[(mt * 16 + ml) * 72 + kk * 32 + qd * 8];
            bf16x8 b = *(const bf16x8*)&wbs[(nt * 16 + ml) * 72 + kk * 32 + qd * 8];
            acc = __builtin_amdgcn_mfma_f32_16x16x32_bf16(a, b, acc, 0, 0, 0);
        }
    }
    const float ssb = s_sbf[0];
#pragma unroll
    for (int r = 0; r < 4; r++) {
        int e = mt * 16 + qd * 4 + r, o = nt * 16 + ml;
        x[(size_t)(e0 + e) * QO + o] = acc[r] * ssb;
    }
}

// ---------------- k5: out = (silu(x@Wca) + silu(x[swap]@Wac)) / sqrt(2) -----
__global__ __launch_bounds__(256) void k5(const float* __restrict__ x,
                                          const float* __restrict__ Wca,
                                          const float* __restrict__ Wac,
                                          const int* __restrict__ swp,
                                          float* __restrict__ outp)
{
    constexpr int BM = 128, BN = 128, LP = 40;  // K = 32 exactly one MFMA
    __shared__ __bf16 Aca[BM * LP];
    __shared__ __bf16 Aac[BM * LP];
    __shared__ __bf16 Bca[BN * LP];
    __shared__ __bf16 Bac[BN * LP];

    const int tid = threadIdx.x;
    const int lane = tid & 63, wv = tid >> 6;
    const int ml = lane & 15, qd = lane >> 4;
    const int row0 = blockIdx.x * BM, col0 = blockIdx.y * BN;
    const int wm = (wv >> 1) * 64, wn = (wv & 1) * 64;

#pragma unroll
    for (int f = tid; f < BM * 8; f += 256) {
        int r = f >> 3, c4 = (f & 7) * 4;
        int grow = row0 + r;
        float4 v = make_float4(0.f, 0.f, 0.f, 0.f);
        float4 w = make_float4(0.f, 0.f, 0.f, 0.f);
        if (grow < NE) {
            v = *(const float4*)(x + (size_t)grow * QI + c4);
            int sr = swp[grow];
            w = *(const float4*)(x + (size_t)sr * QI + c4);
        }
        __bf16* dv = &Aca[r * LP + c4];
        dv[0] = (__bf16)v.x; dv[1] = (__bf16)v.y; dv[2] = (__bf16)v.z; dv[3] = (__bf16)v.w;
        __bf16* dw = &Aac[r * LP + c4];
        dw[0] = (__bf16)w.x; dw[1] = (__bf16)w.y; dw[2] = (__bf16)w.z; dw[3] = (__bf16)w.w;
    }
#pragma unroll
    for (int f = tid; f < 1024; f += 256) {
        int kr = f >> 5, c4 = (f & 31) * 4;
        float4 v = *(const float4*)(Wca + (size_t)kr * ED + col0 + c4);
        float4 w = *(const float4*)(Wac + (size_t)kr * ED + col0 + c4);
        Bca[(c4 + 0) * LP + kr] = (__bf16)v.x;
        Bca[(c4 + 1) * LP + kr] = (__bf16)v.y;
        Bca[(c4 + 2) * LP + kr] = (__bf16)v.z;
        Bca[(c4 + 3) * LP + kr] = (__bf16)v.w;
        Bac[(c4 + 0) * LP + kr] = (__bf16)w.x;
        Bac[(c4 + 1) * LP + kr] = (__bf16)w.y;
        Bac[(c4 + 2) * LP + kr] = (__bf16)w.z;
        Bac[(c4 + 3) * LP + kr] = (__bf16)w.w;
    }
    __syncthreads();

    f32x4 aC[4][4], aA[4][4];
    const f32x4 vz = {0.f, 0.f, 0.f, 0.f};
#pragma unroll
    for (int i = 0; i < 4; i++)
#pragma unroll
        for (int j = 0; j < 4; j++) { aC[i][j] = vz; aA[i][j] = vz; }

    bf16x8 afC[4], afA[4], bfC[4], bfA[4];
#pragma unroll
    for (int i = 0; i < 4; i++) {
        afC[i] = *(const bf16x8*)&Aca[(wm + i * 16 + ml) * LP + qd * 8];
        afA[i] = *(const bf16x8*)&Aac[(wm + i * 16 + ml) * LP + qd * 8];
        bfC[i] = *(const bf16x8*)&Bca[(wn + i * 16 + ml) * LP + qd * 8];
        bfA[i] = *(const bf16x8*)&Bac[(wn + i * 16 + ml) * LP + qd * 8];
    }
#pragma unroll
    for (int mt = 0; mt < 4; mt++)
#pragma unroll
        for (int nt = 0; nt < 4; nt++) {
            aC[mt][nt] = __builtin_amdgcn_mfma_f32_16x16x32_bf16(afC[mt], bfC[nt], aC[mt][nt], 0, 0, 0);
            aA[mt][nt] = __builtin_amdgcn_mfma_f32_16x16x32_bf16(afA[mt], bfA[nt], aA[mt][nt], 0, 0, 0);
        }

    const float inv_sqrt2 = 0.70710678118654752440f;
#pragma unroll
    for (int mt = 0; mt < 4; mt++)
#pragma unroll
        for (int r = 0; r < 4; r++) {
            int grow = row0 + wm + mt * 16 + qd * 4 + r;
            if (grow < NE) {
#pragma unroll
                for (int nt = 0; nt < 4; nt++) {
                    int cc = wn + nt * 16 + ml;
                    float v = (silu_f(aC[mt][nt][r]) + silu_f(aA[mt][nt][r])) * inv_sqrt2;
                    outp[(size_t)grow * ED + col0 + cc] = v;
                }
            }
        }
}

// ---------------------------------------------------------------------------
extern "C" void kernel_launch(void* const* d_in, const int* in_sizes, int n_in,
                              void* d_out, int out_size, void* d_ws, size_t ws_size,
                              hipStream_t stream)
{
    (void)in_sizes; (void)n_in; (void)out_size; (void)ws_size;

    const float* mM    = (const float*)d_in[0];
    const float* rad   = (const float*)d_in[1];
    const float* cir   = (const float*)d_in[2];
    const float* sphW1 = (const float*)d_in[3];
    const float* sph   = (const float*)d_in[4];
    const float* Wdb   = (const float*)d_in[5];
    const float* Wrbf  = (const float*)d_in[6];
    const float* Wdown = (const float*)d_in[7];
    const float* Wcbf  = (const float*)d_in[8];
    const float* Wbil  = (const float*)d_in[9];
    const float* Wca   = (const float*)d_in[10];
    const float* Wac   = (const float*)d_in[11];
    const float* s_rbf = (const float*)d_in[12];
    const float* s_cbf = (const float*)d_in[13];
    const float* s_sbf = (const float*)d_in[14];
    const int* trip_in = (const int*)d_in[15];
    const int* t2q     = (const int*)d_in[16];
    const int* swp     = (const int*)d_in[19];

    char* ws = (char*)d_ws;
    __bf16* x1 = (__bf16*)(ws);                  // NE*512 bf16 = 102,400,000 B
    __bf16* x2 = (__bf16*)(ws + 102400000);      // NE*32  bf16 =   6,400,000 B
    __bf16* tt = (__bf16*)(ws + 108800000);      // NT*32  bf16 =  64,000,000 B
    float*  xx = (float*) (ws + 172800000);      // NE*32  f32  =  12,800,000 B

    constexpr int GM = (NE + 127) / 128;  // 782

    k1<<<dim3(GM, 4), 256, 0, stream>>>(mM, rad, Wdb, Wrbf, s_rbf, x1);
    k2<<<GM, 256, 0, stream>>>(x1, Wdown, x2);
    k3<<<NT / 64, 256, 0, stream>>>(cir, Wcbf, s_cbf, trip_in, x2, tt);
    k4<<<NE / 32, 256, 0, stream>>>(tt, sph, sphW1, Wbil, s_sbf, t2q, xx);
    k5<<<dim3(GM, 4), 256, 0, stream>>>(xx, Wca, Wac, swp, (float*)d_out);
}